// Round 1
// baseline (966.493 us; speedup 1.0000x reference)
//
#include <hip/hip_runtime.h>
#include <math.h>

// CRF log-likelihood, B=512, S=512, T=128.
// out = sum_b (path_score_b - log_partition_b)
//
// fwd_kernel: 1 block (128 thr, 2 waves) per batch. Thread j owns tag-column j.
//   E = exp(transitions) kept in 128 VGPRs per thread (col j). Per step:
//   p_j = exp(score_j - sigma) -> LDS (double buffered); one barrier;
//   acc_j = sum_i p[i]*Ecol[i] via broadcast float4 LDS reads + fmac;
//   score_j = sigma + log(acc_j) + em[b,s,j] (masked select).
//   sigma = thread-0 score, 1-step delayed through LDS (valid shift since
//   log(acc) spread <= 0.2 and em spread <= ~11 -> exp args bounded ~e^11).
// num_kernel: path score per batch (gathers), block reduce.
// reduce_kernel: deterministic final sum of 1024 partials from d_ws.

#define T 128
#define SLEN 512
#define BATCH 512

__global__ __launch_bounds__(128) void fwd_kernel(
    const float* __restrict__ em, const int* __restrict__ mask,
    const float* __restrict__ startT, const float* __restrict__ endT,
    const float* __restrict__ trans, float* __restrict__ ws)
{
    const int b = blockIdx.x;
    const int j = threadIdx.x;          // 0..127
    const float* emb = em + (size_t)b * SLEN * T;
    const int* mk = mask + (size_t)b * SLEN;

    // E column j in registers: Ecol[i] = exp(trans[i][j]); coalesced loads.
    float Ecol[T];
#pragma unroll
    for (int i = 0; i < T; ++i) Ecol[i] = __expf(trans[i * T + j]);

    __shared__ __align__(16) float p_sh[2][T];
    __shared__ float sig_sh[2];
    __shared__ float red_sh[2][2];

    float score = startT[j] + emb[j];   // alpha_0
    float sigma = 0.0f;                 // shift; |alpha_0| small, 0 is safe

    // 4-deep emission prefetch pipeline
    float emv[4], emn[4];
#pragma unroll
    for (int k = 0; k < 4; ++k) emv[k] = emb[(1 + k) * T + j];

    for (int s0 = 1; s0 < SLEN; s0 += 4) {
        // prefetch next group (clamped; values unused past SLEN-1)
#pragma unroll
        for (int k = 0; k < 4; ++k) {
            int ss = s0 + 4 + k; ss = (ss < SLEN) ? ss : (SLEN - 1);
            emn[k] = emb[ss * T + j];
        }
#pragma unroll
        for (int k = 0; k < 4; ++k) {
            const int s = s0 + k;
            if (s < SLEN) {            // uniform guard (tail: 511 steps)
                const int cur = s & 1;
                float p = __expf(score - sigma);
                p_sh[cur][j] = p;
                if (j == 0) sig_sh[cur] = score;   // next step's shift
                __syncthreads();
                const float sig_next = sig_sh[cur];
                const float4* pb = (const float4*)(&p_sh[cur][0]);
                float a0 = 0.f, a1 = 0.f, a2 = 0.f, a3 = 0.f;
#pragma unroll
                for (int i = 0; i < T / 4; ++i) {
                    const float4 pv = pb[i];      // broadcast ds_read_b128
                    a0 = fmaf(pv.x, Ecol[4 * i + 0], a0);
                    a1 = fmaf(pv.y, Ecol[4 * i + 1], a1);
                    a2 = fmaf(pv.z, Ecol[4 * i + 2], a2);
                    a3 = fmaf(pv.w, Ecol[4 * i + 3], a3);
                }
                const float acc = (a0 + a1) + (a2 + a3);
                const float nxt = sigma + __logf(acc) + emv[k];
                score = (mk[s] > 0) ? nxt : score;  // mask select
                sigma = sig_next;
            }
        }
#pragma unroll
        for (int k = 0; k < 4; ++k) emv[k] = emn[k];
    }

    // denom_b = logsumexp_j(score_j + endT[j]); exact block reduction
    const float v = score + endT[j];
    const int wid = j >> 6, lane = j & 63;
    float wmax = v;
#pragma unroll
    for (int off = 32; off > 0; off >>= 1)
        wmax = fmaxf(wmax, __shfl_xor(wmax, off, 64));
    if (lane == 0) red_sh[0][wid] = wmax;
    __syncthreads();
    const float M = fmaxf(red_sh[0][0], red_sh[0][1]);
    float wsum = __expf(v - M);
#pragma unroll
    for (int off = 32; off > 0; off >>= 1)
        wsum += __shfl_xor(wsum, off, 64);
    if (lane == 0) red_sh[1][wid] = wsum;
    __syncthreads();
    if (j == 0)
        ws[BATCH + b] = -(M + __logf(red_sh[1][0] + red_sh[1][1]));
}

__global__ __launch_bounds__(256) void num_kernel(
    const float* __restrict__ em, const int* __restrict__ tags,
    const int* __restrict__ mask, const float* __restrict__ startT,
    const float* __restrict__ endT, const float* __restrict__ trans,
    float* __restrict__ ws)
{
    const int b = blockIdx.x;
    const int t = threadIdx.x;          // 0..255
    const int* tg = tags + (size_t)b * SLEN;
    const int* mk = mask + (size_t)b * SLEN;
    const float* emb = em + (size_t)b * SLEN * T;

    float local = 0.f;
    int cnt = 0;
    for (int s = t; s < SLEN; s += 256) {
        const int m = mk[s];
        cnt += (m != 0);
        if (s >= 1 && m > 0)
            local += trans[tg[s - 1] * T + tg[s]] + emb[s * T + tg[s]];
    }
    __shared__ float rf[256];
    __shared__ int ri[256];
    rf[t] = local; ri[t] = cnt;
    __syncthreads();
    for (int off = 128; off > 0; off >>= 1) {
        if (t < off) { rf[t] += rf[t + off]; ri[t] += ri[t + off]; }
        __syncthreads();
    }
    if (t == 0) {
        const int seqlen = ri[0];
        const int t0 = tg[0];
        const int tl = tg[seqlen - 1];
        ws[b] = startT[t0] + emb[t0] + rf[0] + endT[tl];
    }
}

__global__ __launch_bounds__(256) void reduce_kernel(
    const float* __restrict__ ws, float* __restrict__ out)
{
    const int t = threadIdx.x;          // 0..255, one block
    float local = 0.f;
    for (int i = t; i < 2 * BATCH; i += 256) local += ws[i];
    __shared__ float rf[256];
    rf[t] = local;
    __syncthreads();
    for (int off = 128; off > 0; off >>= 1) {
        if (t < off) rf[t] += rf[t + off];
        __syncthreads();
    }
    if (t == 0) out[0] = rf[0];
}

extern "C" void kernel_launch(void* const* d_in, const int* in_sizes, int n_in,
                              void* d_out, int out_size, void* d_ws, size_t ws_size,
                              hipStream_t stream)
{
    const float* emissions = (const float*)d_in[0];
    const int*   tags      = (const int*)d_in[1];
    const int*   mask      = (const int*)d_in[2];
    const float* startT    = (const float*)d_in[3];
    const float* endT      = (const float*)d_in[4];
    const float* trans     = (const float*)d_in[5];
    float* out = (float*)d_out;
    float* ws  = (float*)d_ws;          // 2*BATCH floats of partials

    num_kernel<<<BATCH, 256, 0, stream>>>(emissions, tags, mask, startT, endT, trans, ws);
    fwd_kernel<<<BATCH, 128, 0, stream>>>(emissions, mask, startT, endT, trans, ws);
    reduce_kernel<<<1, 256, 0, stream>>>(ws, out);
}

// Round 2
// 464.089 us; speedup vs baseline: 2.0826x; 2.0826x over previous
//
#include <hip/hip_runtime.h>
#include <math.h>

// CRF log-likelihood, B=512, S=512, T=128.
// fwd_kernel: 1 block (128 thr) per batch. Pair-lane layout: thread
// (g=tid&1, c=tid>>1) owns cols {2c,2c+1} x rows [64g,64g+64) of
// E = exp(transitions), held in 64 float2 = 128 VGPRs (launch_bounds(128,2)
// caps VGPR at 256 to prevent the round-0 spill that gave VGPR_Count=80).
// Per step: 16 broadcast ds_read_b128 of p + 128 fmac; cross-row reduce via
// __shfl_xor(.,1) (lane pair, no barrier); score update; p for next step into
// double-buffered LDS; ONE barrier per step.
// sigma shift = col-0 score delayed 2 steps, broadcast through LDS (valid:
// any consistent shift works; exp args stay < ~e^20, fp32-safe).
// Numerator (path score) folded into fwd tail; reduce_kernel sums 512 partials.

#define T 128
#define SLEN 512
#define BATCH 512

__global__ __launch_bounds__(128, 2) void fwd_kernel(
    const float* __restrict__ em, const int* __restrict__ tags,
    const int* __restrict__ mask, const float* __restrict__ startT,
    const float* __restrict__ endT, const float* __restrict__ trans,
    float* __restrict__ ws)
{
    const int b = blockIdx.x;
    const int tid = threadIdx.x;
    const int g = tid & 1;          // row half: rows [64g, 64g+64)
    const int c = tid >> 1;         // column pair: cols 2c, 2c+1
    const float* emb = em + (size_t)b * SLEN * T;
    const int* mk = mask + (size_t)b * SLEN;

    // E fragment in registers: E[i] = exp(trans[64g+i][2c .. 2c+1])
    float2 E[64];
    {
        const float* tbase = trans + (64 * g) * T + 2 * c;
#pragma unroll
        for (int i = 0; i < 64; ++i) {
            float2 t = *(const float2*)(tbase + i * T);
            E[i].x = __expf(t.x);
            E[i].y = __expf(t.y);
        }
    }

    __shared__ __align__(16) float p_sh[2][T];
    __shared__ float sig_sh[2];
    __shared__ float red_sh[4];
    __shared__ float nred[2];
    __shared__ int   cred[2];

    // alpha_0
    float2 e0 = *(const float2*)(emb + 2 * c);
    float score0 = startT[2 * c] + e0.x;
    float score1 = startT[2 * c + 1] + e0.y;
    float sigma = 0.f;              // shift used to build p for step 1
    if (g == 0)
        *(float2*)&p_sh[1][2 * c] = make_float2(__expf(score0), __expf(score1));
    if (tid == 0) sig_sh[1] = score0;   // shift for p(2)

    // 4-deep emission/mask prefetch
    float2 emv[4], emn[4];
    int mkv[4], mkn[4];
#pragma unroll
    for (int k = 0; k < 4; ++k) {
        emv[k] = *(const float2*)(emb + (1 + k) * T + 2 * c);
        mkv[k] = mk[1 + k];
    }
    __syncthreads();

    for (int s0 = 1; s0 < SLEN; s0 += 4) {
#pragma unroll
        for (int k = 0; k < 4; ++k) {
            int ss = s0 + 4 + k; ss = (ss < SLEN) ? ss : (SLEN - 1);
            emn[k] = *(const float2*)(emb + ss * T + 2 * c);
            mkn[k] = mk[ss];
        }
#pragma unroll
        for (int k = 0; k < 4; ++k) {
            const int s = s0 + k;
            if (s < SLEN) {                      // uniform guard (511 steps)
                const int cur = s & 1;
                const float4* pb = (const float4*)&p_sh[cur][g * 64];
                float a0 = 0.f, a1 = 0.f, b0 = 0.f, b1 = 0.f;
#pragma unroll
                for (int i = 0; i < 16; ++i) {
                    const float4 pv = pb[i];     // broadcast read, 2-way (free)
                    a0 = fmaf(pv.x, E[4*i+0].x, a0); b0 = fmaf(pv.x, E[4*i+0].y, b0);
                    a1 = fmaf(pv.y, E[4*i+1].x, a1); b1 = fmaf(pv.y, E[4*i+1].y, b1);
                    a0 = fmaf(pv.z, E[4*i+2].x, a0); b0 = fmaf(pv.z, E[4*i+2].y, b0);
                    a1 = fmaf(pv.w, E[4*i+3].x, a1); b1 = fmaf(pv.w, E[4*i+3].y, b1);
                }
                float acc0 = a0 + a1, acc1 = b0 + b1;
                float t0 = acc0 + __shfl_xor(acc0, 1);   // full-column sums,
                float t1 = acc1 + __shfl_xor(acc1, 1);   // both pair lanes
                const float sig_next = sig_sh[cur];      // = score_0(s-1)
                float n0 = sigma + __logf(t0) + emv[k].x;
                float n1 = sigma + __logf(t1) + emv[k].y;
                const bool mv = mkv[k] > 0;
                score0 = mv ? n0 : score0;
                score1 = mv ? n1 : score1;
                float pp0 = __expf(score0 - sig_next);
                float pp1 = __expf(score1 - sig_next);
                if (g == 0)
                    *(float2*)&p_sh[cur ^ 1][2 * c] = make_float2(pp0, pp1);
                if (tid == 0) sig_sh[cur ^ 1] = score0;
                sigma = sig_next;
                __syncthreads();
            }
        }
#pragma unroll
        for (int k = 0; k < 4; ++k) { emv[k] = emn[k]; mkv[k] = mkn[k]; }
    }

    // ---- denominator: logsumexp_j(score_j + endT_j), exact block reduce ----
    const int wid = tid >> 6, lane = tid & 63;
    float v0 = score0 + endT[2 * c];
    float v1 = score1 + endT[2 * c + 1];
    float vm = fmaxf(v0, v1);
#pragma unroll
    for (int off = 32; off; off >>= 1) vm = fmaxf(vm, __shfl_xor(vm, off));
    if (lane == 0) red_sh[wid] = vm;
    __syncthreads();
    const float M = fmaxf(red_sh[0], red_sh[1]);
    float ssum = (g == 0) ? (__expf(v0 - M) + __expf(v1 - M)) : 0.f;
#pragma unroll
    for (int off = 32; off; off >>= 1) ssum += __shfl_xor(ssum, off);
    if (lane == 0) red_sh[2 + wid] = ssum;

    // ---- numerator: path score (gathers), strided over steps ----
    const int* tg = tags + (size_t)b * SLEN;
    float nsum = 0.f; int cnt = 0;
    for (int s = tid; s < SLEN; s += 128) {
        const int m = mk[s];
        cnt += (m != 0);
        if (s >= 1 && m > 0)
            nsum += trans[tg[s - 1] * T + tg[s]] + emb[s * T + tg[s]];
    }
#pragma unroll
    for (int off = 32; off; off >>= 1) {
        nsum += __shfl_xor(nsum, off);
        cnt  += __shfl_xor(cnt, off);
    }
    if (lane == 0) { nred[wid] = nsum; cred[wid] = cnt; }
    __syncthreads();
    if (tid == 0) {
        const float denom = M + __logf(red_sh[2] + red_sh[3]);
        const int seqlen = cred[0] + cred[1];
        const int t0 = tg[0];
        const int tl = tg[seqlen - 1];
        const float num = startT[t0] + emb[t0] + endT[tl] + nred[0] + nred[1];
        ws[b] = num - denom;
    }
}

__global__ __launch_bounds__(256) void reduce_kernel(
    const float* __restrict__ ws, float* __restrict__ out)
{
    const int t = threadIdx.x;          // one block of 256
    float local = 0.f;
    for (int i = t; i < BATCH; i += 256) local += ws[i];
    __shared__ float rf[256];
    rf[t] = local;
    __syncthreads();
    for (int off = 128; off > 0; off >>= 1) {
        if (t < off) rf[t] += rf[t + off];
        __syncthreads();
    }
    if (t == 0) out[0] = rf[0];
}

extern "C" void kernel_launch(void* const* d_in, const int* in_sizes, int n_in,
                              void* d_out, int out_size, void* d_ws, size_t ws_size,
                              hipStream_t stream)
{
    const float* emissions = (const float*)d_in[0];
    const int*   tags      = (const int*)d_in[1];
    const int*   mask      = (const int*)d_in[2];
    const float* startT    = (const float*)d_in[3];
    const float* endT      = (const float*)d_in[4];
    const float* trans     = (const float*)d_in[5];
    float* out = (float*)d_out;
    float* ws  = (float*)d_ws;          // BATCH floats of per-batch partials

    fwd_kernel<<<BATCH, 128, 0, stream>>>(emissions, tags, mask, startT, endT, trans, ws);
    reduce_kernel<<<1, 256, 0, stream>>>(ws, out);
}